// Round 2
// baseline (219.663 us; speedup 1.0000x reference)
//
#include <hip/hip_runtime.h>

typedef __bf16 bf16;
typedef __bf16 bf16x8 __attribute__((ext_vector_type(8)));
typedef float f32x4 __attribute__((ext_vector_type(4)));
typedef unsigned long long u64;

#define MFMA16(a, b, c) __builtin_amdgcn_mfma_f32_16x16x32_bf16(a, b, c, 0, 0, 0)

// Async global->LDS, 16 B/lane; LDS dest = wave-uniform base + lane*16.
__device__ __forceinline__ void gl_lds16(const void* g, void* l) {
  __builtin_amdgcn_global_load_lds(
      (const __attribute__((address_space(1))) unsigned int*)g,
      (__attribute__((address_space(3))) unsigned int*)l, 16, 0, 0);
}

// ---------------------------------------------------------------------------
// Fused prep:
//   blocks    0..1023: weight transpose+downcast (Wq,Wkv -> BqkvT; Wp -> WpT)
//   blocks 1024..1279: mask pack -> u64 bit-words
//   blocks 1280..3327: context f32 -> bf16 (cb)
//   blocks 3328..5375: x f32 -> bf16 (xb)
// ---------------------------------------------------------------------------
__global__ __launch_bounds__(256)
void prep_k(const float* __restrict__ Wq, const float* __restrict__ Wkv,
            const float* __restrict__ Wp, const int* __restrict__ mask,
            const float* __restrict__ context, const float* __restrict__ x,
            bf16* __restrict__ BqkvT, bf16* __restrict__ WpT,
            u64* __restrict__ maskbits, bf16* __restrict__ cb,
            bf16* __restrict__ xb) {
  const int bx = blockIdx.x;
  const int tid = threadIdx.x;
  if (bx >= 3328) {  // ---- x downcast
    const size_t i = ((size_t)(bx - 3328) * 256 + tid) * 8;
    f32x4 a0 = *(const f32x4*)(x + i);
    f32x4 a1 = *(const f32x4*)(x + i + 4);
    bf16x8 t;
#pragma unroll
    for (int j = 0; j < 4; ++j) { t[j] = (bf16)a0[j]; t[4 + j] = (bf16)a1[j]; }
    *(bf16x8*)(xb + i) = t;
    return;
  }
  if (bx >= 1280) {  // ---- context downcast
    const size_t i = ((size_t)(bx - 1280) * 256 + tid) * 8;
    f32x4 a0 = *(const f32x4*)(context + i);
    f32x4 a1 = *(const f32x4*)(context + i + 4);
    bf16x8 t;
#pragma unroll
    for (int j = 0; j < 4; ++j) { t[j] = (bf16)a0[j]; t[4 + j] = (bf16)a1[j]; }
    *(bf16x8*)(cb + i) = t;
    return;
  }
  if (bx >= 1024) {  // ---- mask pack
    const int idx = (bx - 1024) * 256 + tid;
    const int4* p = (const int4*)(mask + (size_t)idx * 64);
    u64 v = 0;
#pragma unroll
    for (int i = 0; i < 16; ++i) {
      int4 m = p[i];
      v |= (u64)(m.x != 0) << (4 * i);
      v |= (u64)(m.y != 0) << (4 * i + 1);
      v |= (u64)(m.z != 0) << (4 * i + 2);
      v |= (u64)(m.w != 0) << (4 * i + 3);
    }
    maskbits[idx] = v;
    return;
  }
  // ---- weight transpose tile
  const int ct = bx >> 4, rt = bx & 15;
  const float* src;
  bf16* dst;
  int C, c0, drow0;
  if (ct < 16) {
    src = Wq; C = 1024; c0 = ct * 64; dst = BqkvT; drow0 = c0;
  } else if (ct < 48) {
    src = Wkv; C = 2048; c0 = (ct - 16) * 64; dst = BqkvT; drow0 = 1024 + c0;
  } else {
    src = Wp; C = 1024; c0 = (ct - 48) * 64; dst = WpT; drow0 = c0;
  }
  __shared__ bf16 T[64][72];
  const int r0 = rt * 64;
#pragma unroll
  for (int i = 0; i < 2; ++i) {
    int c = i * 256 + tid;
    int row = c >> 3, col = (c & 7) * 8;
    const float* sp = &src[(size_t)(r0 + row) * C + c0 + col];
    f32x4 a0 = *(const f32x4*)sp;
    f32x4 a1 = *(const f32x4*)(sp + 4);
    bf16x8 t;
#pragma unroll
    for (int j = 0; j < 4; ++j) { t[j] = (bf16)a0[j]; t[4 + j] = (bf16)a1[j]; }
    *(bf16x8*)&T[row][col] = t;
  }
  __syncthreads();
#pragma unroll
  for (int i = 0; i < 2; ++i) {
    int c = i * 256 + tid;
    int orow = c >> 3, ocol = (c & 7) * 8;
    bf16x8 v;
#pragma unroll
    for (int j = 0; j < 8; ++j) v[j] = T[ocol + j][orow];
    *(bf16x8*)&dst[(size_t)(drow0 + orow) * 1024 + r0 + ocol] = v;
  }
}

// ---------------------------------------------------------------------------
// Double-buffered GEMM v2: 128(M)xBN(N) tile, BK=32, single barrier per
// K-step (tile k+1's global_load_lds stays in flight across tile k's MFMAs,
// draining at the next barrier). LDS: As 2x8KB + Bs 2x(BN/16)KB = 32 KB
// (BN=128) / 24 KB (BN=64); __launch_bounds__(256,3) pins 3 blocks/CU.
// BK=32 rows are 64 B -> 8-way bank conflict if linear; fixed by a 16B-
// granule XOR swizzle (phys_c = c ^ ((row>>1)&3)) applied on the per-lane
// GLOBAL source address (LDS dest of global_load_lds must stay linear) and
// identically on the ds_read column -> 2-way aliasing = free.
// 4 waves in 2x2; each wave 64 x BN/2 out, 16 (BN=128) or 8 MFMA per K-step
// vs 8/6 ds_read_b128. XCD grid: blockIdx.x = m-block -> XCD = m%8.
//   EPI 1 (QKV): A = xb (q cols) / cb (kv cols). Scatters Q*SCALE2/K/V^T.
//   EPI 0 (OP):  A = aow, writes f32 out.
// ---------------------------------------------------------------------------
template <int EPI, int BN>
__global__ __launch_bounds__(256, 3)
void gemm_db2(const bf16* __restrict__ A0, const bf16* __restrict__ A1,
              const bf16* __restrict__ Bt, const float* __restrict__ bias0,
              const float* __restrict__ bias1, bf16* __restrict__ oq,
              bf16* __restrict__ ok, bf16* __restrict__ ovt,
              float* __restrict__ outf) {
  constexpr int NJ = BN / 32;  // 16-wide n-frags per wave
  __shared__ bf16 As[2][128][32];
  __shared__ bf16 Bs[2][BN][32];
  const int tid = threadIdx.x;
  const int lane = tid & 63;
  const int w = tid >> 6;
  const int wm = (w >> 1) * 64;
  const int wn = (w & 1) * (BN / 2);
  const int l15 = lane & 15, l4 = lane >> 4;
  // Staging coords: 4 lanes/row (16 B each), granule-swizzled source column.
  const int lrow = lane >> 2;
  const int lcg = (lane & 3) ^ ((lrow >> 1) & 3);
  // ds_read column (elems): same XOR keyed on the row the lane reads (l15).
  const int rdc = (l4 ^ ((l15 >> 1) & 3)) * 8;
  const int m0 = blockIdx.x * 128;  // m fastest -> XCD = m%8
  const int n0 = blockIdx.y * BN;

  const bf16* Asrc = (EPI == 1) ? ((n0 < 1024) ? A0 : A1) : A0;

  f32x4 acc[4][NJ] = {};

#define STAGE(kk, buf)                                                        \
  {                                                                           \
    _Pragma("unroll") for (int it = 0; it < 2; ++it) {                        \
      const int r = w * 32 + it * 16;                                         \
      gl_lds16(&Asrc[(size_t)(m0 + r + lrow) * 1024 + (kk) + lcg * 8],        \
               &As[buf][r][0]);                                               \
    }                                                                         \
    _Pragma("unroll") for (int it = 0; it < BN / 64; ++it) {                  \
      const int r = w * (BN / 4) + it * 16;                                   \
      gl_lds16(&Bt[(size_t)(n0 + r + lrow) * 1024 + (kk) + lcg * 8],          \
               &Bs[buf][r][0]);                                               \
    }                                                                         \
  }

#define COMPUTE(buf)                                                          \
  {                                                                           \
    bf16x8 af[4], bfr[NJ];                                                    \
    _Pragma("unroll") for (int i = 0; i < 4; ++i) af[i] =                     \
        *(const bf16x8*)&As[buf][wm + i * 16 + l15][rdc];                     \
    _Pragma("unroll") for (int j = 0; j < NJ; ++j) bfr[j] =                   \
        *(const bf16x8*)&Bs[buf][wn + j * 16 + l15][rdc];                     \
    _Pragma("unroll") for (int i = 0; i < 4; ++i)                             \
        _Pragma("unroll") for (int j = 0; j < NJ; ++j) acc[i][j] =            \
            MFMA16(af[i], bfr[j], acc[i][j]);                                 \
  }

  // Prologue: stage K-step 0 into buffer 0.
  STAGE(0, 0);
  for (int k = 0; k < 32; k += 2) {
    __syncthreads();  // drains staging for buf0 (k)
    STAGE((k + 1) * 32, 1);  // in flight across COMPUTE(0)
    COMPUTE(0);
    __syncthreads();  // drains staging for buf1 (k+1)
    if (k < 30) STAGE((k + 2) * 32, 0);
    COMPUTE(1);
  }
#undef STAGE
#undef COMPUTE

  const float SCALE2 = 0.18033688011112042f;  // 1/sqrt(64) * log2(e)
#pragma unroll
  for (int j = 0; j < NJ; ++j) {
    const int col = n0 + wn + j * 16 + l15;
    float bc;
    if (EPI == 1) bc = (col < 1024) ? bias0[col] : bias1[col - 1024];
    else bc = bias0[col];
#pragma unroll
    for (int i = 0; i < 4; ++i) {
#pragma unroll
      for (int r = 0; r < 4; ++r) {
        const int row = m0 + wm + i * 16 + l4 * 4 + r;
        const float v = acc[i][j][r] + bc;
        if (EPI == 0) {
          outf[(size_t)row * 1024 + col] = v;
        } else {
          const int b = row >> 10, n = row & 1023;
          if (col < 1024) {
            const int h = col >> 6, d = col & 63;
            oq[(((size_t)(b * 16 + h)) * 1024 + n) * 64 + d] =
                (bf16)(v * SCALE2);
          } else {
            const int ckv = col - 1024;
            const int s = ckv >> 10, c2 = ckv & 1023;
            const int h = c2 >> 6, d = c2 & 63;
            if (s == 0)
              ok[(((size_t)(b * 16 + h)) * 1024 + n) * 64 + d] = (bf16)v;
            else
              ovt[(((size_t)(b * 16 + h)) * 64 + d) * 1024 + n] = (bf16)v;
          }
        }
      }
    }
  }
}

// ---------------------------------------------------------------------------
// Flash-style masked attention, fixed-max softmax, bit-packed mask, XCD grid
// (bh fastest). Unchanged.
// ---------------------------------------------------------------------------
__global__ __launch_bounds__(256)
void attn_kernel(const bf16* __restrict__ q, const bf16* __restrict__ k,
                 const bf16* __restrict__ vT, const u64* __restrict__ maskbits,
                 bf16* __restrict__ ao) {
  const int bh = blockIdx.x;
  const int ntile = blockIdx.y;
  const int b = bh >> 4, h = bh & 15;
  const int tid = threadIdx.x;
  const int lane = tid & 63;
  const int w = tid >> 6;
  const int l15 = lane & 15, l4 = lane >> 4;

  __shared__ bf16 Ks[64][72];
  __shared__ bf16 Vts[64][72];
  __shared__ bf16 Pw[4][16][72];

  const size_t base = (size_t)bh * 65536;
  const int nrow0 = ntile * 64 + w * 16;

  bf16x8 qf[2];
#pragma unroll
  for (int ks = 0; ks < 2; ++ks)
    qf[ks] =
        *(const bf16x8*)&q[base + (size_t)(nrow0 + l15) * 64 + ks * 32 + l4 * 8];

  f32x4 o[4] = {};
  float lsum[4] = {0.0f, 0.0f, 0.0f, 0.0f};

  const u64* mb = maskbits + (size_t)(b * 1024 + nrow0) * 16;

  for (int mt = 0; mt < 16; ++mt) {
#pragma unroll
    for (int i = 0; i < 2; ++i) {
      int c = i * 256 + tid;
      int row = c >> 3, col = (c & 7) * 8;
      *(bf16x8*)&Ks[row][col] =
          *(const bf16x8*)&k[base + (size_t)(mt * 64 + row) * 64 + col];
      *(bf16x8*)&Vts[row][col] =
          *(const bf16x8*)&vT[base + (size_t)row * 1024 + mt * 64 + col];
    }
    __syncthreads();

    f32x4 s[4];
#pragma unroll
    for (int sub = 0; sub < 4; ++sub) s[sub] = f32x4{-12.f, -12.f, -12.f, -12.f};
#pragma unroll
    for (int ks = 0; ks < 2; ++ks) {
#pragma unroll
      for (int sub = 0; sub < 4; ++sub) {
        bf16x8 bfr = *(const bf16x8*)&Ks[sub * 16 + l15][ks * 32 + l4 * 8];
        s[sub] = MFMA16(qf[ks], bfr, s[sub]);
      }
    }

    u64 wbits[4];
#pragma unroll
    for (int r = 0; r < 4; ++r) wbits[r] = mb[(size_t)(l4 * 4 + r) * 16 + mt];

#pragma unroll
    for (int sub = 0; sub < 4; ++sub) {
#pragma unroll
      for (int r = 0; r < 4; ++r) {
        float p = exp2f(s[sub][r]);
        p = ((wbits[r] >> (sub * 16 + l15)) & 1) ? p : 0.0f;
        lsum[r] += p;
        Pw[w][l4 * 4 + r][sub * 16 + l15] = (bf16)p;
      }
    }

#pragma unroll
    for (int ks = 0; ks < 2; ++ks) {
      bf16x8 af = *(const bf16x8*)&Pw[w][l15][ks * 32 + l4 * 8];
#pragma unroll
      for (int sub = 0; sub < 4; ++sub) {
        bf16x8 bfr = *(const bf16x8*)&Vts[sub * 16 + l15][ks * 32 + l4 * 8];
        o[sub] = MFMA16(af, bfr, o[sub]);
      }
    }
    __syncthreads();
  }

  float inv[4];
#pragma unroll
  for (int r = 0; r < 4; ++r) {
    float t = lsum[r];
#pragma unroll
    for (int d = 1; d < 16; d <<= 1) t += __shfl_xor(t, d);
    inv[r] = 1.0f / t;
  }

#pragma unroll
  for (int sub = 0; sub < 4; ++sub) {
#pragma unroll
    for (int r = 0; r < 4; ++r) {
      const int n = nrow0 + l4 * 4 + r;
      const size_t idx =
          ((size_t)(b * 1024 + n)) * 1024 + h * 64 + sub * 16 + l15;
      ao[idx] = (bf16)(o[sub][r] * inv[r]);
    }
  }
}

// ---------------------------------------------------------------------------
extern "C" void kernel_launch(void* const* d_in, const int* in_sizes, int n_in,
                              void* d_out, int out_size, void* d_ws,
                              size_t ws_size, hipStream_t stream) {
  const float* x = (const float*)d_in[0];        // [4,1024,1024]
  const float* context = (const float*)d_in[1];  // [4,1024,1024]
  const int* mask = (const int*)d_in[2];         // [4,1024,32,32]
  const float* Wq = (const float*)d_in[3];
  const float* bq = (const float*)d_in[4];
  const float* Wkv = (const float*)d_in[5];
  const float* bkv = (const float*)d_in[6];
  const float* Wp = (const float*)d_in[7];
  const float* bp = (const float*)d_in[8];
  float* out = (float*)d_out;                    // [4,1024,1024] f32

  // Workspace (48.5 MB):
  //  @0    (8 MB): cb (prep->QKV), dead after QKV -> aow reuses it
  //  @8    (8 MB): xb (prep->QKV), dead after QKV
  //  @16   (6 MB): BqkvT (prep->QKV)
  //  @22   (8 MB): qw   @30 (8 MB): kw   @38 (8 MB): vtw
  //  @46 (0.5 MB): maskbits   @46.5 (2 MB): WpT
  char* ws = (char*)d_ws;
  bf16* cb = (bf16*)(ws);
  bf16* aow = (bf16*)(ws);
  bf16* xb = (bf16*)(ws + (8ull << 20));
  bf16* BqkvT = (bf16*)(ws + (16ull << 20));
  bf16* qw = (bf16*)(ws + (22ull << 20));
  bf16* kw = (bf16*)(ws + (30ull << 20));
  bf16* vtw = (bf16*)(ws + (38ull << 20));
  u64* maskbits = (u64*)(ws + (46ull << 20));
  bf16* WpT = (bf16*)(ws + (46ull << 20) + (512ull << 10));

  const dim3 blk(256);

  // Prep: weight transposes + mask pack + context/x downcast, one launch.
  prep_k<<<dim3(5376), blk, 0, stream>>>(Wq, Wkv, Wp, mask, context, x, BqkvT,
                                         WpT, maskbits, cb, xb);

  // Fused QKV projection: dbuf v2 128x128 BK=32, grid (m=32, n=24), 3 blk/CU.
  gemm_db2<1, 128><<<dim3(32, 24), blk, 0, stream>>>(xb, cb, BqkvT, bq, bkv,
                                                     qw, kw, vtw, nullptr);

  // Attention: grid (bh=64, ntile=16) -> XCD = bh%8.
  attn_kernel<<<dim3(64, 16), blk, 0, stream>>>(qw, kw, vtw, maskbits, aow);

  // Output projection: dbuf v2 128x64 BK=32, grid (m=32, n=16), 2 blk/CU.
  gemm_db2<0, 64><<<dim3(32, 16), blk, 0, stream>>>(aow, nullptr, WpT, bp,
                                                    nullptr, nullptr, nullptr,
                                                    nullptr, out);
}

// Round 3
// 211.631 us; speedup vs baseline: 1.0380x; 1.0380x over previous
//
#include <hip/hip_runtime.h>

typedef __bf16 bf16;
typedef __bf16 bf16x8 __attribute__((ext_vector_type(8)));
typedef __bf16 bf16x4 __attribute__((ext_vector_type(4)));
typedef float f32x4 __attribute__((ext_vector_type(4)));
typedef unsigned long long u64;

#define MFMA16(a, b, c) __builtin_amdgcn_mfma_f32_16x16x32_bf16(a, b, c, 0, 0, 0)

// Async global->LDS, 16 B/lane; LDS dest = wave-uniform base + lane*16.
__device__ __forceinline__ void gl_lds16(const void* g, void* l) {
  __builtin_amdgcn_global_load_lds(
      (const __attribute__((address_space(1))) unsigned int*)g,
      (__attribute__((address_space(3))) unsigned int*)l, 16, 0, 0);
}

// ---------------------------------------------------------------------------
// Fused prep:
//   blocks    0..1023: weight transpose+downcast (Wq,Wkv -> BqkvT; Wp -> WpT)
//   blocks 1024..1279: mask pack -> u64 bit-words
//   blocks 1280..3327: context f32 -> bf16 (cb)
//   blocks 3328..5375: x f32 -> bf16 (xb)
// ---------------------------------------------------------------------------
__global__ __launch_bounds__(256)
void prep_k(const float* __restrict__ Wq, const float* __restrict__ Wkv,
            const float* __restrict__ Wp, const int* __restrict__ mask,
            const float* __restrict__ context, const float* __restrict__ x,
            bf16* __restrict__ BqkvT, bf16* __restrict__ WpT,
            u64* __restrict__ maskbits, bf16* __restrict__ cb,
            bf16* __restrict__ xb) {
  const int bx = blockIdx.x;
  const int tid = threadIdx.x;
  if (bx >= 3328) {  // ---- x downcast
    const size_t i = ((size_t)(bx - 3328) * 256 + tid) * 8;
    f32x4 a0 = *(const f32x4*)(x + i);
    f32x4 a1 = *(const f32x4*)(x + i + 4);
    bf16x8 t;
#pragma unroll
    for (int j = 0; j < 4; ++j) { t[j] = (bf16)a0[j]; t[4 + j] = (bf16)a1[j]; }
    *(bf16x8*)(xb + i) = t;
    return;
  }
  if (bx >= 1280) {  // ---- context downcast
    const size_t i = ((size_t)(bx - 1280) * 256 + tid) * 8;
    f32x4 a0 = *(const f32x4*)(context + i);
    f32x4 a1 = *(const f32x4*)(context + i + 4);
    bf16x8 t;
#pragma unroll
    for (int j = 0; j < 4; ++j) { t[j] = (bf16)a0[j]; t[4 + j] = (bf16)a1[j]; }
    *(bf16x8*)(cb + i) = t;
    return;
  }
  if (bx >= 1024) {  // ---- mask pack
    const int idx = (bx - 1024) * 256 + tid;
    const int4* p = (const int4*)(mask + (size_t)idx * 64);
    u64 v = 0;
#pragma unroll
    for (int i = 0; i < 16; ++i) {
      int4 m = p[i];
      v |= (u64)(m.x != 0) << (4 * i);
      v |= (u64)(m.y != 0) << (4 * i + 1);
      v |= (u64)(m.z != 0) << (4 * i + 2);
      v |= (u64)(m.w != 0) << (4 * i + 3);
    }
    maskbits[idx] = v;
    return;
  }
  // ---- weight transpose tile
  const int ct = bx >> 4, rt = bx & 15;
  const float* src;
  bf16* dst;
  int C, c0, drow0;
  if (ct < 16) {
    src = Wq; C = 1024; c0 = ct * 64; dst = BqkvT; drow0 = c0;
  } else if (ct < 48) {
    src = Wkv; C = 2048; c0 = (ct - 16) * 64; dst = BqkvT; drow0 = 1024 + c0;
  } else {
    src = Wp; C = 1024; c0 = (ct - 48) * 64; dst = WpT; drow0 = c0;
  }
  __shared__ bf16 T[64][72];
  const int r0 = rt * 64;
#pragma unroll
  for (int i = 0; i < 2; ++i) {
    int c = i * 256 + tid;
    int row = c >> 3, col = (c & 7) * 8;
    const float* sp = &src[(size_t)(r0 + row) * C + c0 + col];
    f32x4 a0 = *(const f32x4*)sp;
    f32x4 a1 = *(const f32x4*)(sp + 4);
    bf16x8 t;
#pragma unroll
    for (int j = 0; j < 4; ++j) { t[j] = (bf16)a0[j]; t[4 + j] = (bf16)a1[j]; }
    *(bf16x8*)&T[row][col] = t;
  }
  __syncthreads();
#pragma unroll
  for (int i = 0; i < 2; ++i) {
    int c = i * 256 + tid;
    int orow = c >> 3, ocol = (c & 7) * 8;
    bf16x8 v;
#pragma unroll
    for (int j = 0; j < 8; ++j) v[j] = T[ocol + j][orow];
    *(bf16x8*)&dst[(size_t)(drow0 + orow) * 1024 + r0 + ocol] = v;
  }
}

// ---------------------------------------------------------------------------
// Double-buffered GEMM v2 (unchanged from round 2): 128(M)xBN(N), BK=32,
// single barrier per K-step, 16B-granule XOR swizzle, 3 blocks/CU.
// ---------------------------------------------------------------------------
template <int EPI, int BN>
__global__ __launch_bounds__(256, 3)
void gemm_db2(const bf16* __restrict__ A0, const bf16* __restrict__ A1,
              const bf16* __restrict__ Bt, const float* __restrict__ bias0,
              const float* __restrict__ bias1, bf16* __restrict__ oq,
              bf16* __restrict__ ok, bf16* __restrict__ ovt,
              float* __restrict__ outf) {
  constexpr int NJ = BN / 32;  // 16-wide n-frags per wave
  __shared__ bf16 As[2][128][32];
  __shared__ bf16 Bs[2][BN][32];
  const int tid = threadIdx.x;
  const int lane = tid & 63;
  const int w = tid >> 6;
  const int wm = (w >> 1) * 64;
  const int wn = (w & 1) * (BN / 2);
  const int l15 = lane & 15, l4 = lane >> 4;
  // Staging coords: 4 lanes/row (16 B each), granule-swizzled source column.
  const int lrow = lane >> 2;
  const int lcg = (lane & 3) ^ ((lrow >> 1) & 3);
  // ds_read column (elems): same XOR keyed on the row the lane reads (l15).
  const int rdc = (l4 ^ ((l15 >> 1) & 3)) * 8;
  const int m0 = blockIdx.x * 128;  // m fastest -> XCD = m%8
  const int n0 = blockIdx.y * BN;

  const bf16* Asrc = (EPI == 1) ? ((n0 < 1024) ? A0 : A1) : A0;

  f32x4 acc[4][NJ] = {};

#define STAGE(kk, buf)                                                        \
  {                                                                           \
    _Pragma("unroll") for (int it = 0; it < 2; ++it) {                        \
      const int r = w * 32 + it * 16;                                         \
      gl_lds16(&Asrc[(size_t)(m0 + r + lrow) * 1024 + (kk) + lcg * 8],        \
               &As[buf][r][0]);                                               \
    }                                                                         \
    _Pragma("unroll") for (int it = 0; it < BN / 64; ++it) {                  \
      const int r = w * (BN / 4) + it * 16;                                   \
      gl_lds16(&Bt[(size_t)(n0 + r + lrow) * 1024 + (kk) + lcg * 8],          \
               &Bs[buf][r][0]);                                               \
    }                                                                         \
  }

#define COMPUTE(buf)                                                          \
  {                                                                           \
    bf16x8 af[4], bfr[NJ];                                                    \
    _Pragma("unroll") for (int i = 0; i < 4; ++i) af[i] =                     \
        *(const bf16x8*)&As[buf][wm + i * 16 + l15][rdc];                     \
    _Pragma("unroll") for (int j = 0; j < NJ; ++j) bfr[j] =                   \
        *(const bf16x8*)&Bs[buf][wn + j * 16 + l15][rdc];                     \
    _Pragma("unroll") for (int i = 0; i < 4; ++i)                             \
        _Pragma("unroll") for (int j = 0; j < NJ; ++j) acc[i][j] =            \
            MFMA16(af[i], bfr[j], acc[i][j]);                                 \
  }

  // Prologue: stage K-step 0 into buffer 0.
  STAGE(0, 0);
  for (int k = 0; k < 32; k += 2) {
    __syncthreads();  // drains staging for buf0 (k)
    STAGE((k + 1) * 32, 1);  // in flight across COMPUTE(0)
    COMPUTE(0);
    __syncthreads();  // drains staging for buf1 (k+1)
    if (k < 30) STAGE((k + 2) * 32, 0);
    COMPUTE(1);
  }
#undef STAGE
#undef COMPUTE

  const float SCALE2 = 0.18033688011112042f;  // 1/sqrt(64) * log2(e)
#pragma unroll
  for (int j = 0; j < NJ; ++j) {
    const int col = n0 + wn + j * 16 + l15;
    float bc;
    if (EPI == 1) bc = (col < 1024) ? bias0[col] : bias1[col - 1024];
    else bc = bias0[col];
#pragma unroll
    for (int i = 0; i < 4; ++i) {
#pragma unroll
      for (int r = 0; r < 4; ++r) {
        const int row = m0 + wm + i * 16 + l4 * 4 + r;
        const float v = acc[i][j][r] + bc;
        if (EPI == 0) {
          outf[(size_t)row * 1024 + col] = v;
        } else {
          const int b = row >> 10, n = row & 1023;
          if (col < 1024) {
            const int h = col >> 6, d = col & 63;
            oq[(((size_t)(b * 16 + h)) * 1024 + n) * 64 + d] =
                (bf16)(v * SCALE2);
          } else {
            const int ckv = col - 1024;
            const int s = ckv >> 10, c2 = ckv & 1023;
            const int h = c2 >> 6, d = c2 & 63;
            if (s == 0)
              ok[(((size_t)(b * 16 + h)) * 1024 + n) * 64 + d] = (bf16)v;
            else
              ovt[(((size_t)(b * 16 + h)) * 64 + d) * 1024 + n] = (bf16)v;
          }
        }
      }
    }
  }
}

// ---------------------------------------------------------------------------
// Attention v2: swapped QK^T (S^T = mfma(K,Q)) so each lane owns ONE q-row
// (l15) and 16 k-values -> P pack is 4x ds_write_b64 (was 16x conflicted
// ds_write_b16), 1 mask u64/lane/mt (was 4), scalar lsum (+2 end shuffles).
// K/V staged via global_load_lds into zero-pad [64][64] tiles, 16B-granule
// XOR swizzle (phys = g ^ (row&7)) applied on per-lane GLOBAL source and on
// all ds_read/ds_write columns -> conflict-free. Double-buffered, ONE
// barrier per mt (stage mt+1 in flight across compute mt).
// LDS = 2*8K*2 + 8K = 40960 B -> exactly 4 blocks/CU; grid 1024 = 4/CU.
// ---------------------------------------------------------------------------
__global__ __launch_bounds__(256, 4)
void attn_kernel(const bf16* __restrict__ q, const bf16* __restrict__ k,
                 const bf16* __restrict__ vT, const u64* __restrict__ maskbits,
                 bf16* __restrict__ ao) {
  const int bh = blockIdx.x;
  const int ntile = blockIdx.y;
  const int b = bh >> 4, h = bh & 15;
  const int tid = threadIdx.x;
  const int lane = tid & 63;
  const int w = tid >> 6;
  const int l15 = lane & 15, l4 = lane >> 4;

  __shared__ bf16 Ks[2][64][64];
  __shared__ bf16 Vts[2][64][64];
  __shared__ bf16 Pw[4][16][64];

  const size_t base = (size_t)bh * 65536;
  const int nrow0 = ntile * 64 + w * 16;

  // Q B-fragments (n=q-row=l15, kdim d = ks*32 + l4*8 + j). Pre-scaled.
  bf16x8 qf[2];
#pragma unroll
  for (int ks = 0; ks < 2; ++ks)
    qf[ks] = *(const bf16x8*)&q[base + (size_t)(nrow0 + l15) * 64 + ks * 32 +
                                l4 * 8];

  // Per-lane mask row (q-row = l15); one u64 per mt.
  const u64* mb = maskbits + (size_t)(b * 1024 + nrow0 + l15) * 16;

  // Staging: lane i -> row base+ (i>>3), phys granule i&7; source fetches
  // logical granule (i&7)^(row&7) so that phys = logical ^ (row&7).
  const int srow = lane >> 3;                // 0..7
  const int sgl = (lane & 7) ^ srow;         // logical granule to fetch
  const bf16* kp = &k[base + (size_t)(w * 16 + srow) * 64 + sgl * 8];
  const bf16* vp = &vT[base + (size_t)(w * 16 + srow) * 1024 + sgl * 8];

  // Fragment read columns: logical granule ks*4+l4 -> phys ^= (l15&7).
  const int rc0 = ((0 + l4) ^ (l15 & 7)) * 8;
  const int rc1 = ((4 + l4) ^ (l15 & 7)) * 8;

  f32x4 o[4] = {};
  float lsum = 0.0f;

#define STAGEA(mt_, buf_)                                                     \
  {                                                                           \
    _Pragma("unroll") for (int it = 0; it < 2; ++it) {                        \
      gl_lds16(kp + (size_t)((mt_)*64 + it * 8) * 64,                         \
               &Ks[buf_][w * 16 + it * 8][0]);                                \
      gl_lds16(vp + (size_t)(it * 8) * 1024 + (mt_)*64,                       \
               &Vts[buf_][w * 16 + it * 8][0]);                               \
    }                                                                         \
  }

  STAGEA(0, 0);
  for (int mt = 0; mt < 16; ++mt) {
    const int cur = mt & 1;
    __syncthreads();  // drains staging for tile mt
    if (mt < 15) STAGEA(mt + 1, cur ^ 1);  // in flight across compute
    const u64 wmt = mb[mt];

    // S^T: lane holds q = l15, k = sub*16 + l4*4 + r. Same LDS reads as
    // before; only the operand order is swapped (K is the A-operand).
    f32x4 s[4];
#pragma unroll
    for (int sub = 0; sub < 4; ++sub)
      s[sub] = f32x4{-12.f, -12.f, -12.f, -12.f};
    __builtin_amdgcn_s_setprio(1);
#pragma unroll
    for (int sub = 0; sub < 4; ++sub) {
      bf16x8 kf0 = *(const bf16x8*)&Ks[cur][sub * 16 + l15][rc0];
      bf16x8 kf1 = *(const bf16x8*)&Ks[cur][sub * 16 + l15][rc1];
      s[sub] = MFMA16(kf0, qf[0], s[sub]);
      s[sub] = MFMA16(kf1, qf[1], s[sub]);
    }
    __builtin_amdgcn_s_setprio(0);

    // Softmax + P pack: 4 contiguous k-values -> one ds_write_b64 per sub.
#pragma unroll
    for (int sub = 0; sub < 4; ++sub) {
      const int kbit = sub * 16 + l4 * 4;
      float p[4];
#pragma unroll
      for (int r = 0; r < 4; ++r) {
        float e = exp2f(s[sub][r]);
        p[r] = ((wmt >> (kbit + r)) & 1) ? e : 0.0f;
      }
      lsum += (p[0] + p[1]) + (p[2] + p[3]);
      bf16x4 pv;
#pragma unroll
      for (int r = 0; r < 4; ++r) pv[r] = (bf16)p[r];
      // k0 = sub*16 + l4*4: granule gw = sub*2 + (l4>>1), half = l4&1.
      const int gw = sub * 2 + (l4 >> 1);
      char* pd = (char*)&Pw[w][l15][0] + ((gw ^ (l15 & 7)) * 16 + (l4 & 1) * 8);
      *(bf16x4*)pd = pv;
    }

    // PV: A = P (row=q=l15, kdim = ks*32+l4*8+j), B = V (n=d=l15).
    bf16x8 af0 = *(const bf16x8*)&Pw[w][l15][rc0];
    bf16x8 af1 = *(const bf16x8*)&Pw[w][l15][rc1];
    __builtin_amdgcn_s_setprio(1);
#pragma unroll
    for (int sub = 0; sub < 4; ++sub) {
      bf16x8 vf0 = *(const bf16x8*)&Vts[cur][sub * 16 + l15][rc0];
      bf16x8 vf1 = *(const bf16x8*)&Vts[cur][sub * 16 + l15][rc1];
      o[sub] = MFMA16(af0, vf0, o[sub]);
      o[sub] = MFMA16(af1, vf1, o[sub]);
    }
    __builtin_amdgcn_s_setprio(0);
  }
#undef STAGEA

  // lsum lives at lane (q=l15): reduce over l4-groups, then shuffle to the
  // output layout (q = l4*4 + r).
  float t = lsum;
  t += __shfl_xor(t, 16);
  t += __shfl_xor(t, 32);
  float inv[4];
#pragma unroll
  for (int r = 0; r < 4; ++r) inv[r] = 1.0f / __shfl(t, l4 * 4 + r);

#pragma unroll
  for (int sub = 0; sub < 4; ++sub) {
#pragma unroll
    for (int r = 0; r < 4; ++r) {
      const int n = nrow0 + l4 * 4 + r;
      const size_t idx =
          ((size_t)(b * 1024 + n)) * 1024 + h * 64 + sub * 16 + l15;
      ao[idx] = (bf16)(o[sub][r] * inv[r]);
    }
  }
}

// ---------------------------------------------------------------------------
extern "C" void kernel_launch(void* const* d_in, const int* in_sizes, int n_in,
                              void* d_out, int out_size, void* d_ws,
                              size_t ws_size, hipStream_t stream) {
  const float* x = (const float*)d_in[0];        // [4,1024,1024]
  const float* context = (const float*)d_in[1];  // [4,1024,1024]
  const int* mask = (const int*)d_in[2];         // [4,1024,32,32]
  const float* Wq = (const float*)d_in[3];
  const float* bq = (const float*)d_in[4];
  const float* Wkv = (const float*)d_in[5];
  const float* bkv = (const float*)d_in[6];
  const float* Wp = (const float*)d_in[7];
  const float* bp = (const float*)d_in[8];
  float* out = (float*)d_out;                    // [4,1024,1024] f32

  // Workspace (48.5 MB):
  //  @0    (8 MB): cb (prep->QKV), dead after QKV -> aow reuses it
  //  @8    (8 MB): xb (prep->QKV), dead after QKV
  //  @16   (6 MB): BqkvT (prep->QKV)
  //  @22   (8 MB): qw   @30 (8 MB): kw   @38 (8 MB): vtw
  //  @46 (0.5 MB): maskbits   @46.5 (2 MB): WpT
  char* ws = (char*)d_ws;
  bf16* cb = (bf16*)(ws);
  bf16* aow = (bf16*)(ws);
  bf16* xb = (bf16*)(ws + (8ull << 20));
  bf16* BqkvT = (bf16*)(ws + (16ull << 20));
  bf16* qw = (bf16*)(ws + (22ull << 20));
  bf16* kw = (bf16*)(ws + (30ull << 20));
  bf16* vtw = (bf16*)(ws + (38ull << 20));
  u64* maskbits = (u64*)(ws + (46ull << 20));
  bf16* WpT = (bf16*)(ws + (46ull << 20) + (512ull << 10));

  const dim3 blk(256);

  // Prep: weight transposes + mask pack + context/x downcast, one launch.
  prep_k<<<dim3(5376), blk, 0, stream>>>(Wq, Wkv, Wp, mask, context, x, BqkvT,
                                         WpT, maskbits, cb, xb);

  // Fused QKV projection: dbuf v2 128x128 BK=32, grid (m=32, n=24), 3 blk/CU.
  gemm_db2<1, 128><<<dim3(32, 24), blk, 0, stream>>>(xb, cb, BqkvT, bq, bkv,
                                                     qw, kw, vtw, nullptr);

  // Attention v2: grid (bh=64, ntile=16) -> XCD = bh%8.
  attn_kernel<<<dim3(64, 16), blk, 0, stream>>>(qw, kw, vtw, maskbits, aow);

  // Output projection: dbuf v2 128x64 BK=32, grid (m=32, n=16), 2 blk/CU.
  gemm_db2<0, 64><<<dim3(32, 16), blk, 0, stream>>>(aow, nullptr, WpT, bp,
                                                    nullptr, nullptr, nullptr,
                                                    nullptr, out);
}

// Round 4
// 209.290 us; speedup vs baseline: 1.0496x; 1.0112x over previous
//
#include <hip/hip_runtime.h>

typedef __bf16 bf16;
typedef __bf16 bf16x8 __attribute__((ext_vector_type(8)));
typedef __bf16 bf16x4 __attribute__((ext_vector_type(4)));
typedef float f32x4 __attribute__((ext_vector_type(4)));
typedef unsigned long long u64;

#define MFMA16(a, b, c) __builtin_amdgcn_mfma_f32_16x16x32_bf16(a, b, c, 0, 0, 0)

// Async global->LDS, 16 B/lane; LDS dest = wave-uniform base + lane*16.
__device__ __forceinline__ void gl_lds16(const void* g, void* l) {
  __builtin_amdgcn_global_load_lds(
      (const __attribute__((address_space(1))) unsigned int*)g,
      (__attribute__((address_space(3))) unsigned int*)l, 16, 0, 0);
}

template <int N>
__device__ __forceinline__ void wait_vmcnt() {
  asm volatile("s_waitcnt vmcnt(%0)" ::"n"(N) : "memory");
}

// Compiler-fenced raw barrier (no vmcnt drain, unlike __syncthreads).
__device__ __forceinline__ void bar() {
  asm volatile("" ::: "memory");
  __builtin_amdgcn_s_barrier();
  asm volatile("" ::: "memory");
}

// ---------------------------------------------------------------------------
// Fused prep:
//   blocks    0..1023: weight transpose+downcast (Wq,Wkv -> BqkvT; Wp -> WpT)
//   blocks 1024..1279: mask pack -> u64 bit-words
//   blocks 1280..3327: context f32 -> bf16 (cb)
//   blocks 3328..5375: x f32 -> bf16 (xb)
// ---------------------------------------------------------------------------
__global__ __launch_bounds__(256)
void prep_k(const float* __restrict__ Wq, const float* __restrict__ Wkv,
            const float* __restrict__ Wp, const int* __restrict__ mask,
            const float* __restrict__ context, const float* __restrict__ x,
            bf16* __restrict__ BqkvT, bf16* __restrict__ WpT,
            u64* __restrict__ maskbits, bf16* __restrict__ cb,
            bf16* __restrict__ xb) {
  const int bx = blockIdx.x;
  const int tid = threadIdx.x;
  if (bx >= 3328) {  // ---- x downcast
    const size_t i = ((size_t)(bx - 3328) * 256 + tid) * 8;
    f32x4 a0 = *(const f32x4*)(x + i);
    f32x4 a1 = *(const f32x4*)(x + i + 4);
    bf16x8 t;
#pragma unroll
    for (int j = 0; j < 4; ++j) { t[j] = (bf16)a0[j]; t[4 + j] = (bf16)a1[j]; }
    *(bf16x8*)(xb + i) = t;
    return;
  }
  if (bx >= 1280) {  // ---- context downcast
    const size_t i = ((size_t)(bx - 1280) * 256 + tid) * 8;
    f32x4 a0 = *(const f32x4*)(context + i);
    f32x4 a1 = *(const f32x4*)(context + i + 4);
    bf16x8 t;
#pragma unroll
    for (int j = 0; j < 4; ++j) { t[j] = (bf16)a0[j]; t[4 + j] = (bf16)a1[j]; }
    *(bf16x8*)(cb + i) = t;
    return;
  }
  if (bx >= 1024) {  // ---- mask pack
    const int idx = (bx - 1024) * 256 + tid;
    const int4* p = (const int4*)(mask + (size_t)idx * 64);
    u64 v = 0;
#pragma unroll
    for (int i = 0; i < 16; ++i) {
      int4 m = p[i];
      v |= (u64)(m.x != 0) << (4 * i);
      v |= (u64)(m.y != 0) << (4 * i + 1);
      v |= (u64)(m.z != 0) << (4 * i + 2);
      v |= (u64)(m.w != 0) << (4 * i + 3);
    }
    maskbits[idx] = v;
    return;
  }
  // ---- weight transpose tile
  const int ct = bx >> 4, rt = bx & 15;
  const float* src;
  bf16* dst;
  int C, c0, drow0;
  if (ct < 16) {
    src = Wq; C = 1024; c0 = ct * 64; dst = BqkvT; drow0 = c0;
  } else if (ct < 48) {
    src = Wkv; C = 2048; c0 = (ct - 16) * 64; dst = BqkvT; drow0 = 1024 + c0;
  } else {
    src = Wp; C = 1024; c0 = (ct - 48) * 64; dst = WpT; drow0 = c0;
  }
  __shared__ bf16 T[64][72];
  const int r0 = rt * 64;
#pragma unroll
  for (int i = 0; i < 2; ++i) {
    int c = i * 256 + tid;
    int row = c >> 3, col = (c & 7) * 8;
    const float* sp = &src[(size_t)(r0 + row) * C + c0 + col];
    f32x4 a0 = *(const f32x4*)sp;
    f32x4 a1 = *(const f32x4*)(sp + 4);
    bf16x8 t;
#pragma unroll
    for (int j = 0; j < 4; ++j) { t[j] = (bf16)a0[j]; t[4 + j] = (bf16)a1[j]; }
    *(bf16x8*)&T[row][col] = t;
  }
  __syncthreads();
#pragma unroll
  for (int i = 0; i < 2; ++i) {
    int c = i * 256 + tid;
    int orow = c >> 3, ocol = (c & 7) * 8;
    bf16x8 v;
#pragma unroll
    for (int j = 0; j < 8; ++j) v[j] = T[ocol + j][orow];
    *(bf16x8*)&dst[(size_t)(drow0 + orow) * 1024 + r0 + ocol] = v;
  }
}

// ---------------------------------------------------------------------------
// Pipelined GEMM v3: 128(M)xBN(N) tile, BK=32, THREE LDS buffers (tile t ->
// buf t%3), stages issued 2 tiles ahead, ONE raw barrier per K-step with
// counted s_waitcnt vmcnt(S) (S = loads/thread/stage; never 0 in the loop).
// The tile-k-ready barrier also certifies buf (k-1)%3 free for STAGE(k+2):
// every wave's ds_reads of tile k-1 completed before it reached barrier k
// (MFMA consumption forces lgkmcnt). Bias preloaded BEFORE first STAGE so
// no compiler vmem op can corrupt the vmcnt accounting.
// 16B-granule XOR swizzle on global source + ds_read column (0 conflicts).
// LDS: BN=128 -> 48 KB (3 blk/CU); BN=64 -> 36 KB (4 blk/CU).
//   EPI 1 (QKV): A = xb (q cols) / cb (kv cols). Scatters Q*SCALE2/K/V^T.
//   EPI 0 (OP):  A = aow, writes f32 out.
// ---------------------------------------------------------------------------
template <int EPI, int BN>
__global__ __launch_bounds__(256, BN == 128 ? 3 : 4)
void gemm_p3(const bf16* __restrict__ A0, const bf16* __restrict__ A1,
             const bf16* __restrict__ Bt, const float* __restrict__ bias0,
             const float* __restrict__ bias1, bf16* __restrict__ oq,
             bf16* __restrict__ ok, bf16* __restrict__ ovt,
             float* __restrict__ outf) {
  constexpr int NJ = BN / 32;      // 16-wide n-frags per wave
  constexpr int S = 2 + BN / 64;   // global_load_lds per thread per stage
  __shared__ bf16 As[3][128][32];
  __shared__ bf16 Bs[3][BN][32];
  const int tid = threadIdx.x;
  const int lane = tid & 63;
  const int w = tid >> 6;
  const int wm = (w >> 1) * 64;
  const int wn = (w & 1) * (BN / 2);
  const int l15 = lane & 15, l4 = lane >> 4;
  // Staging coords: 4 lanes/row (16 B each), granule-swizzled source column.
  const int lrow = lane >> 2;
  const int lcg = (lane & 3) ^ ((lrow >> 1) & 3);
  // ds_read column (elems): same XOR keyed on the row the lane reads (l15).
  const int rdc = (l4 ^ ((l15 >> 1) & 3)) * 8;
  const int m0 = blockIdx.x * 128;  // m fastest -> XCD = m%8
  const int n0 = blockIdx.y * BN;

  const bf16* Asrc = (EPI == 1) ? ((n0 < 1024) ? A0 : A1) : A0;

  // Preload bias (issued before any staging -> retires before first wait).
  float bc[NJ];
#pragma unroll
  for (int j = 0; j < NJ; ++j) {
    const int col = n0 + wn + j * 16 + l15;
    if (EPI == 1) bc[j] = (col < 1024) ? bias0[col] : bias1[col - 1024];
    else bc[j] = bias0[col];
  }

  f32x4 acc[4][NJ] = {};

#define STAGE(kk, buf)                                                        \
  {                                                                           \
    _Pragma("unroll") for (int it = 0; it < 2; ++it) {                        \
      const int r = w * 32 + it * 16;                                         \
      gl_lds16(&Asrc[(size_t)(m0 + r + lrow) * 1024 + (kk) + lcg * 8],        \
               &As[buf][r][0]);                                               \
    }                                                                         \
    _Pragma("unroll") for (int it = 0; it < BN / 64; ++it) {                  \
      const int r = w * (BN / 4) + it * 16;                                   \
      gl_lds16(&Bt[(size_t)(n0 + r + lrow) * 1024 + (kk) + lcg * 8],          \
               &Bs[buf][r][0]);                                               \
    }                                                                         \
  }

#define COMPUTE(buf)                                                          \
  {                                                                           \
    bf16x8 af[4], bfr[NJ];                                                    \
    _Pragma("unroll") for (int i = 0; i < 4; ++i) af[i] =                     \
        *(const bf16x8*)&As[buf][wm + i * 16 + l15][rdc];                     \
    _Pragma("unroll") for (int j = 0; j < NJ; ++j) bfr[j] =                   \
        *(const bf16x8*)&Bs[buf][wn + j * 16 + l15][rdc];                     \
    _Pragma("unroll") for (int i = 0; i < 4; ++i)                             \
        _Pragma("unroll") for (int j = 0; j < NJ; ++j) acc[i][j] =            \
            MFMA16(af[i], bfr[j], acc[i][j]);                                 \
  }

  // Prologue: tiles 0 and 1 in flight (2S outstanding).
  STAGE(0, 0);
  STAGE(32, 1);
#pragma unroll 3
  for (int k = 0; k < 30; ++k) {
    wait_vmcnt<S>();  // tile k landed; tile k+1 stays in flight
    bar();
    STAGE((k + 2) * 32, (k + 2) % 3);  // buf free: tile k-1 fully read
    COMPUTE(k % 3);
  }
  // k = 30: tile 31 stays in flight across compute.
  wait_vmcnt<S>();
  bar();
  COMPUTE(0);
  // k = 31: final tile, drain.
  wait_vmcnt<0>();
  bar();
  COMPUTE(1);
#undef STAGE
#undef COMPUTE

  const float SCALE2 = 0.18033688011112042f;  // 1/sqrt(64) * log2(e)
#pragma unroll
  for (int j = 0; j < NJ; ++j) {
    const int col = n0 + wn + j * 16 + l15;
#pragma unroll
    for (int i = 0; i < 4; ++i) {
#pragma unroll
      for (int r = 0; r < 4; ++r) {
        const int row = m0 + wm + i * 16 + l4 * 4 + r;
        const float v = acc[i][j][r] + bc[j];
        if (EPI == 0) {
          outf[(size_t)row * 1024 + col] = v;
        } else {
          const int b = row >> 10, n = row & 1023;
          if (col < 1024) {
            const int h = col >> 6, d = col & 63;
            oq[(((size_t)(b * 16 + h)) * 1024 + n) * 64 + d] =
                (bf16)(v * SCALE2);
          } else {
            const int ckv = col - 1024;
            const int s = ckv >> 10, c2 = ckv & 1023;
            const int h = c2 >> 6, d = c2 & 63;
            if (s == 0)
              ok[(((size_t)(b * 16 + h)) * 1024 + n) * 64 + d] = (bf16)v;
            else
              ovt[(((size_t)(b * 16 + h)) * 64 + d) * 1024 + n] = (bf16)v;
          }
        }
      }
    }
  }
}

// ---------------------------------------------------------------------------
// Attention v2 (unchanged from round 3): swapped QK^T, ds_write_b64 P-pack,
// 1 mask u64/lane/mt, global_load_lds K/V staging with XOR swizzle, dbuf,
// one __syncthreads per mt. LDS 40960 B -> 4 blocks/CU.
// ---------------------------------------------------------------------------
__global__ __launch_bounds__(256, 4)
void attn_kernel(const bf16* __restrict__ q, const bf16* __restrict__ k,
                 const bf16* __restrict__ vT, const u64* __restrict__ maskbits,
                 bf16* __restrict__ ao) {
  const int bh = blockIdx.x;
  const int ntile = blockIdx.y;
  const int b = bh >> 4, h = bh & 15;
  const int tid = threadIdx.x;
  const int lane = tid & 63;
  const int w = tid >> 6;
  const int l15 = lane & 15, l4 = lane >> 4;

  __shared__ bf16 Ks[2][64][64];
  __shared__ bf16 Vts[2][64][64];
  __shared__ bf16 Pw[4][16][64];

  const size_t base = (size_t)bh * 65536;
  const int nrow0 = ntile * 64 + w * 16;

  // Q B-fragments (n=q-row=l15, kdim d = ks*32 + l4*8 + j). Pre-scaled.
  bf16x8 qf[2];
#pragma unroll
  for (int ks = 0; ks < 2; ++ks)
    qf[ks] = *(const bf16x8*)&q[base + (size_t)(nrow0 + l15) * 64 + ks * 32 +
                                l4 * 8];

  // Per-lane mask row (q-row = l15); one u64 per mt.
  const u64* mb = maskbits + (size_t)(b * 1024 + nrow0 + l15) * 16;

  // Staging: lane i -> row base+(i>>3), phys granule i&7; source fetches
  // logical granule (i&7)^(row&7) so that phys = logical ^ (row&7).
  const int srow = lane >> 3;                // 0..7
  const int sgl = (lane & 7) ^ srow;         // logical granule to fetch
  const bf16* kp = &k[base + (size_t)(w * 16 + srow) * 64 + sgl * 8];
  const bf16* vp = &vT[base + (size_t)(w * 16 + srow) * 1024 + sgl * 8];

  // Fragment read columns: logical granule ks*4+l4 -> phys ^= (l15&7).
  const int rc0 = ((0 + l4) ^ (l15 & 7)) * 8;
  const int rc1 = ((4 + l4) ^ (l15 & 7)) * 8;

  f32x4 o[4] = {};
  float lsum = 0.0f;

#define STAGEA(mt_, buf_)                                                     \
  {                                                                           \
    _Pragma("unroll") for (int it = 0; it < 2; ++it) {                        \
      gl_lds16(kp + (size_t)((mt_)*64 + it * 8) * 64,                         \
               &Ks[buf_][w * 16 + it * 8][0]);                                \
      gl_lds16(vp + (size_t)(it * 8) * 1024 + (mt_)*64,                       \
               &Vts[buf_][w * 16 + it * 8][0]);                               \
    }                                                                         \
  }

  STAGEA(0, 0);
  for (int mt = 0; mt < 16; ++mt) {
    const int cur = mt & 1;
    __syncthreads();  // drains staging for tile mt
    if (mt < 15) STAGEA(mt + 1, cur ^ 1);  // in flight across compute
    const u64 wmt = mb[mt];

    // S^T: lane holds q = l15, k = sub*16 + l4*4 + r.
    f32x4 s[4];
#pragma unroll
    for (int sub = 0; sub < 4; ++sub)
      s[sub] = f32x4{-12.f, -12.f, -12.f, -12.f};
    __builtin_amdgcn_s_setprio(1);
#pragma unroll
    for (int sub = 0; sub < 4; ++sub) {
      bf16x8 kf0 = *(const bf16x8*)&Ks[cur][sub * 16 + l15][rc0];
      bf16x8 kf1 = *(const bf16x8*)&Ks[cur][sub * 16 + l15][rc1];
      s[sub] = MFMA16(kf0, qf[0], s[sub]);
      s[sub] = MFMA16(kf1, qf[1], s[sub]);
    }
    __builtin_amdgcn_s_setprio(0);

    // Softmax + P pack: 4 contiguous k-values -> one ds_write_b64 per sub.
#pragma unroll
    for (int sub = 0; sub < 4; ++sub) {
      const int kbit = sub * 16 + l4 * 4;
      float p[4];
#pragma unroll
      for (int r = 0; r < 4; ++r) {
        float e = exp2f(s[sub][r]);
        p[r] = ((wmt >> (kbit + r)) & 1) ? e : 0.0f;
      }
      lsum += (p[0] + p[1]) + (p[2] + p[3]);
      bf16x4 pv;
#pragma unroll
      for (int r = 0; r < 4; ++r) pv[r] = (bf16)p[r];
      const int gw = sub * 2 + (l4 >> 1);
      char* pd = (char*)&Pw[w][l15][0] + ((gw ^ (l15 & 7)) * 16 + (l4 & 1) * 8);
      *(bf16x4*)pd = pv;
    }

    // PV: A = P (row=q=l15), B = V (n=d=l15).
    bf16x8 af0 = *(const bf16x8*)&Pw[w][l15][rc0];
    bf16x8 af1 = *(const bf16x8*)&Pw[w][l15][rc1];
    __builtin_amdgcn_s_setprio(1);
#pragma unroll
    for (int sub = 0; sub < 4; ++sub) {
      bf16x8 vf0 = *(const bf16x8*)&Vts[cur][sub * 16 + l15][rc0];
      bf16x8 vf1 = *(const bf16x8*)&Vts[cur][sub * 16 + l15][rc1];
      o[sub] = MFMA16(af0, vf0, o[sub]);
      o[sub] = MFMA16(af1, vf1, o[sub]);
    }
    __builtin_amdgcn_s_setprio(0);
  }
#undef STAGEA

  float t = lsum;
  t += __shfl_xor(t, 16);
  t += __shfl_xor(t, 32);
  float inv[4];
#pragma unroll
  for (int r = 0; r < 4; ++r) inv[r] = 1.0f / __shfl(t, l4 * 4 + r);

#pragma unroll
  for (int sub = 0; sub < 4; ++sub) {
#pragma unroll
    for (int r = 0; r < 4; ++r) {
      const int n = nrow0 + l4 * 4 + r;
      const size_t idx =
          ((size_t)(b * 1024 + n)) * 1024 + h * 64 + sub * 16 + l15;
      ao[idx] = (bf16)(o[sub][r] * inv[r]);
    }
  }
}

// ---------------------------------------------------------------------------
extern "C" void kernel_launch(void* const* d_in, const int* in_sizes, int n_in,
                              void* d_out, int out_size, void* d_ws,
                              size_t ws_size, hipStream_t stream) {
  const float* x = (const float*)d_in[0];        // [4,1024,1024]
  const float* context = (const float*)d_in[1];  // [4,1024,1024]
  const int* mask = (const int*)d_in[2];         // [4,1024,32,32]
  const float* Wq = (const float*)d_in[3];
  const float* bq = (const float*)d_in[4];
  const float* Wkv = (const float*)d_in[5];
  const float* bkv = (const float*)d_in[6];
  const float* Wp = (const float*)d_in[7];
  const float* bp = (const float*)d_in[8];
  float* out = (float*)d_out;                    // [4,1024,1024] f32

  // Workspace (48.5 MB):
  //  @0    (8 MB): cb (prep->QKV), dead after QKV -> aow reuses it
  //  @8    (8 MB): xb (prep->QKV), dead after QKV
  //  @16   (6 MB): BqkvT (prep->QKV)
  //  @22   (8 MB): qw   @30 (8 MB): kw   @38 (8 MB): vtw
  //  @46 (0.5 MB): maskbits   @46.5 (2 MB): WpT
  char* ws = (char*)d_ws;
  bf16* cb = (bf16*)(ws);
  bf16* aow = (bf16*)(ws);
  bf16* xb = (bf16*)(ws + (8ull << 20));
  bf16* BqkvT = (bf16*)(ws + (16ull << 20));
  bf16* qw = (bf16*)(ws + (22ull << 20));
  bf16* kw = (bf16*)(ws + (30ull << 20));
  bf16* vtw = (bf16*)(ws + (38ull << 20));
  u64* maskbits = (u64*)(ws + (46ull << 20));
  bf16* WpT = (bf16*)(ws + (46ull << 20) + (512ull << 10));

  const dim3 blk(256);

  // Prep: weight transposes + mask pack + context/x downcast, one launch.
  prep_k<<<dim3(5376), blk, 0, stream>>>(Wq, Wkv, Wp, mask, context, x, BqkvT,
                                         WpT, maskbits, cb, xb);

  // Fused QKV projection: pipelined v3, grid (m=32, n=24), 3 blk/CU.
  gemm_p3<1, 128><<<dim3(32, 24), blk, 0, stream>>>(xb, cb, BqkvT, bq, bkv,
                                                    qw, kw, vtw, nullptr);

  // Attention v2: grid (bh=64, ntile=16) -> XCD = bh%8.
  attn_kernel<<<dim3(64, 16), blk, 0, stream>>>(qw, kw, vtw, maskbits, aow);

  // Output projection: pipelined v3, grid (m=32, n=16), 4 blk/CU.
  gemm_p3<0, 64><<<dim3(32, 16), blk, 0, stream>>>(aow, nullptr, WpT, bp,
                                                   nullptr, nullptr, nullptr,
                                                   nullptr, out);
}